// Round 1
// baseline (16989.494 us; speedup 1.0000x reference)
//
#include <hip/hip_runtime.h>

// LightGCN-style propagation for 3 bipartite graphs (UB, UI, BI).
// Per graph: x = concat(featA, featB); acc = x/3; cur = x;
// 2x { nxt = SpMM(vals, rows, cols, cur); acc += (nxt/||nxt||_row)/3; cur = nxt; }
// acc is written directly into d_out (per-graph regions are contiguous and in
// return order), with the /3 folded into every accumulate.

constexpr int EMB = 64;
constexpr int RD4 = 16;              // float4 chunks per row
constexpr float THIRD = 1.0f / 3.0f;
constexpr float EPS_NRM = 1e-12f;

__global__ void init_concat_kernel(const float* __restrict__ fA,
                                   const float* __restrict__ fB,
                                   int nA, int N,
                                   float* __restrict__ cur,
                                   float* __restrict__ acc) {
    long long total = (long long)N * RD4;
    long long stride = (long long)gridDim.x * blockDim.x;
    long long iA = (long long)nA * RD4;
    for (long long i = blockIdx.x * (long long)blockDim.x + threadIdx.x;
         i < total; i += stride) {
        float4 v = (i < iA) ? ((const float4*)fA)[i] : ((const float4*)fB)[i - iA];
        ((float4*)cur)[i] = v;
        ((float4*)acc)[i] = make_float4(v.x * THIRD, v.y * THIRD, v.z * THIRD, v.w * THIRD);
    }
}

// 16 threads per edge; thread t of an edge handles dims [4t, 4t+4).
__global__ void spmm_atomic_kernel(const int* __restrict__ rows,
                                   const int* __restrict__ cols,
                                   const float* __restrict__ vals,
                                   long long E,
                                   const float* __restrict__ cur,
                                   float* __restrict__ nxt) {
    long long total = E * RD4;
    long long stride = (long long)gridDim.x * blockDim.x;
    for (long long i = blockIdx.x * (long long)blockDim.x + threadIdx.x;
         i < total; i += stride) {
        long long e = i >> 4;
        int d4 = (int)(i & 15);
        int r = rows[e];
        int c = cols[e];
        float v = vals[e];
        float4 g = ((const float4*)cur)[(long long)c * RD4 + d4];
        float* dst = nxt + (long long)r * EMB + d4 * 4;
        atomicAdd(dst + 0, v * g.x);
        atomicAdd(dst + 1, v * g.y);
        atomicAdd(dst + 2, v * g.z);
        atomicAdd(dst + 3, v * g.w);
    }
}

// 16 lanes cooperate on one row (4 rows per wave): row-L2-norm via shfl_xor,
// then acc += (nxt / max(nrm, eps)) / 3.
__global__ void norm_accum_kernel(const float* __restrict__ nxt,
                                  float* __restrict__ acc,
                                  int N) {
    long long total = (long long)N * RD4;
    long long stride = (long long)gridDim.x * blockDim.x;
    for (long long i = blockIdx.x * (long long)blockDim.x + threadIdx.x;
         i < total; i += stride) {
        float4 g = ((const float4*)nxt)[i];
        float ss = g.x * g.x + g.y * g.y + g.z * g.z + g.w * g.w;
        ss += __shfl_xor(ss, 1, 64);
        ss += __shfl_xor(ss, 2, 64);
        ss += __shfl_xor(ss, 4, 64);
        ss += __shfl_xor(ss, 8, 64);
        float scale = THIRD / fmaxf(sqrtf(ss), EPS_NRM);
        float4 a = ((float4*)acc)[i];
        a.x += g.x * scale;
        a.y += g.y * scale;
        a.z += g.z * scale;
        a.w += g.w * scale;
        ((float4*)acc)[i] = a;
    }
}

static inline int grid_for(long long total, int block) {
    long long g = (total + block - 1) / block;
    if (g > (1LL << 20)) g = (1LL << 20);
    if (g < 1) g = 1;
    return (int)g;
}

extern "C" void kernel_launch(void* const* d_in, const int* in_sizes, int n_in,
                              void* d_out, int out_size, void* d_ws, size_t ws_size,
                              hipStream_t stream) {
    const float* fu = (const float*)d_in[0];
    const float* fb = (const float*)d_in[1];
    const float* fi = (const float*)d_in[2];
    const int nU = in_sizes[0] / EMB;
    const int nB = in_sizes[1] / EMB;
    const int nI = in_sizes[2] / EMB;
    float* out = (float*)d_out;

    struct G {
        const int* rows; const int* cols; const float* vals;
        long long E; const float* fA; const float* fB; int nA; int nBn;
    };
    G gs[3] = {
        { (const int*)d_in[3], (const int*)d_in[4], (const float*)d_in[5],
          (long long)in_sizes[3], fu, fb, nU, nB },
        { (const int*)d_in[6], (const int*)d_in[7], (const float*)d_in[8],
          (long long)in_sizes[6], fu, fi, nU, nI },
        { (const int*)d_in[9], (const int*)d_in[10], (const float*)d_in[11],
          (long long)in_sizes[9], fb, fi, nB, nI },
    };

    int maxN = 0;
    for (int gi = 0; gi < 3; ++gi) {
        int N = gs[gi].nA + gs[gi].nBn;
        if (N > maxN) maxN = N;
    }
    float* buf0 = (float*)d_ws;
    float* buf1 = buf0 + (long long)maxN * EMB;

    long long out_off = 0;
    for (int gi = 0; gi < 3; ++gi) {
        const G& g = gs[gi];
        const int N = g.nA + g.nBn;
        float* acc = out + out_off;
        float* cur = buf0;
        float* nxt = buf1;
        const long long rowTot = (long long)N * RD4;

        init_concat_kernel<<<grid_for(rowTot, 256), 256, 0, stream>>>(
            g.fA, g.fB, g.nA, N, cur, acc);

        for (int layer = 0; layer < 2; ++layer) {
            hipMemsetAsync(nxt, 0, (size_t)N * EMB * sizeof(float), stream);
            const long long eTot = g.E * RD4;
            spmm_atomic_kernel<<<grid_for(eTot, 256), 256, 0, stream>>>(
                g.rows, g.cols, g.vals, g.E, cur, nxt);
            norm_accum_kernel<<<grid_for(rowTot, 256), 256, 0, stream>>>(nxt, acc, N);
            float* t = cur; cur = nxt; nxt = t;
        }
        out_off += (long long)N * EMB;
    }
}

// Round 2
// 2611.100 us; speedup vs baseline: 6.5066x; 6.5066x over previous
//
#include <hip/hip_runtime.h>

// LightGCN propagation, 3 bipartite graphs. Round 2: atomic-free SpMM.
// Per call, per graph: build CSR on device (histogram -> 1-block scan ->
// scatter), then 2x fused {gather-SpMM + row-L2-norm + acc += norm/3}.
// acc lives directly in d_out (graph output regions are contiguous).

constexpr int EMB = 64;
constexpr int RD4 = 16;              // float4 chunks per row
constexpr float THIRD = 1.0f / 3.0f;
constexpr float EPS_NRM = 1e-12f;

__global__ void init_concat_kernel(const float* __restrict__ fA,
                                   const float* __restrict__ fB,
                                   int nA, int N,
                                   float* __restrict__ cur,
                                   float* __restrict__ acc) {
    long long total = (long long)N * RD4;
    long long stride = (long long)gridDim.x * blockDim.x;
    long long iA = (long long)nA * RD4;
    for (long long i = blockIdx.x * (long long)blockDim.x + threadIdx.x;
         i < total; i += stride) {
        float4 v = (i < iA) ? ((const float4*)fA)[i] : ((const float4*)fB)[i - iA];
        ((float4*)cur)[i] = v;
        ((float4*)acc)[i] = make_float4(v.x * THIRD, v.y * THIRD, v.z * THIRD, v.w * THIRD);
    }
}

__global__ void hist_kernel(const int* __restrict__ rows, long long E,
                            int* __restrict__ cnt) {
    long long stride = (long long)gridDim.x * blockDim.x;
    for (long long e = blockIdx.x * (long long)blockDim.x + threadIdx.x;
         e < E; e += stride) {
        atomicAdd(&cnt[rows[e]], 1);
    }
}

// Single-block exclusive scan of cnt[0..N) -> ptr[0..N]; also resets
// cnt[i] to the exclusive prefix (serves as the scatter cursor).
__global__ void scan_kernel(int N, int* __restrict__ cnt, int* __restrict__ ptr) {
    __shared__ int sums[1024];
    const int t = threadIdx.x;
    const int chunk = (N + 1023) / 1024;
    const int lo = t * chunk;
    const int hi = min(lo + chunk, N);
    int s = 0;
    for (int i = lo; i < hi; ++i) s += cnt[i];
    sums[t] = s;
    __syncthreads();
    for (int off = 1; off < 1024; off <<= 1) {
        int v = (t >= off) ? sums[t - off] : 0;
        __syncthreads();
        sums[t] += v;
        __syncthreads();
    }
    int run = (t == 0) ? 0 : sums[t - 1];
    for (int i = lo; i < hi; ++i) {
        int c = cnt[i];
        ptr[i] = run;
        cnt[i] = run;   // cursor for scatter
        run += c;
    }
    if (t == 1023) ptr[N] = sums[1023];
}

__global__ void scatter_kernel(const int* __restrict__ rows,
                               const int* __restrict__ cols,
                               const float* __restrict__ vals,
                               long long E,
                               int* __restrict__ cursor,
                               int* __restrict__ ci,
                               float* __restrict__ cv) {
    long long stride = (long long)gridDim.x * blockDim.x;
    for (long long e = blockIdx.x * (long long)blockDim.x + threadIdx.x;
         e < E; e += stride) {
        int r = rows[e];
        int pos = atomicAdd(&cursor[r], 1);
        ci[pos] = cols[e];
        cv[pos] = vals[e];
    }
}

// 16 lanes own one output row (float4 per lane). Gather cur[col] over the
// row's CSR range, then fused: optional nxt write, row-L2-norm via
// quarter-wave shfl_xor, acc += s * (1/3)/max(||s||,eps).
__global__ void spmm_norm_kernel(const int* __restrict__ ptr,
                                 const int* __restrict__ ci,
                                 const float* __restrict__ cv,
                                 const float* __restrict__ cur,
                                 float* __restrict__ nxt,
                                 float* __restrict__ acc,
                                 int N, int writeNext) {
    int gid = (int)((blockIdx.x * (long long)blockDim.x + threadIdx.x) >> 4);
    int lane = threadIdx.x & 15;
    if (gid >= N) return;
    const int beg = ptr[gid];
    const int end = ptr[gid + 1];
    float4 s = make_float4(0.f, 0.f, 0.f, 0.f);
    for (int j = beg; j < end; ++j) {
        int c = ci[j];
        float v = cv[j];
        float4 g = ((const float4*)cur)[(long long)c * RD4 + lane];
        s.x += v * g.x;
        s.y += v * g.y;
        s.z += v * g.z;
        s.w += v * g.w;
    }
    const long long idx = (long long)gid * RD4 + lane;
    if (writeNext) ((float4*)nxt)[idx] = s;
    float ss = s.x * s.x + s.y * s.y + s.z * s.z + s.w * s.w;
    ss += __shfl_xor(ss, 1, 16);
    ss += __shfl_xor(ss, 2, 16);
    ss += __shfl_xor(ss, 4, 16);
    ss += __shfl_xor(ss, 8, 16);
    float scale = THIRD / fmaxf(sqrtf(ss), EPS_NRM);
    float4 a = ((float4*)acc)[idx];
    a.x += s.x * scale;
    a.y += s.y * scale;
    a.z += s.z * scale;
    a.w += s.w * scale;
    ((float4*)acc)[idx] = a;
}

static inline int grid_for(long long total, int block) {
    long long g = (total + block - 1) / block;
    if (g > (1LL << 20)) g = (1LL << 20);
    if (g < 1) g = 1;
    return (int)g;
}

extern "C" void kernel_launch(void* const* d_in, const int* in_sizes, int n_in,
                              void* d_out, int out_size, void* d_ws, size_t ws_size,
                              hipStream_t stream) {
    const float* fu = (const float*)d_in[0];
    const float* fb = (const float*)d_in[1];
    const float* fi = (const float*)d_in[2];
    const int nU = in_sizes[0] / EMB;
    const int nB = in_sizes[1] / EMB;
    const int nI = in_sizes[2] / EMB;
    float* out = (float*)d_out;

    struct G {
        const int* rows; const int* cols; const float* vals;
        long long E; const float* fA; const float* fB; int nA; int nBn;
    };
    G gs[3] = {
        { (const int*)d_in[3], (const int*)d_in[4], (const float*)d_in[5],
          (long long)in_sizes[3], fu, fb, nU, nB },
        { (const int*)d_in[6], (const int*)d_in[7], (const float*)d_in[8],
          (long long)in_sizes[6], fu, fi, nU, nI },
        { (const int*)d_in[9], (const int*)d_in[10], (const float*)d_in[11],
          (long long)in_sizes[9], fb, fi, nB, nI },
    };

    int maxN = 0;
    long long maxE = 0;
    for (int gi = 0; gi < 3; ++gi) {
        int N = gs[gi].nA + gs[gi].nBn;
        if (N > maxN) maxN = N;
        if (gs[gi].E > maxE) maxE = gs[gi].E;
    }

    // Workspace layout (16B-aligned chunks):
    //   buf0, buf1:  maxN*64 floats each    (ping-pong features)
    //   ptr:         maxN+1 ints            (CSR row ptr)
    //   cnt:         maxN+1 ints            (histogram / scatter cursor)
    //   ci:          maxE ints              (CSR col indices)
    //   cv:          maxE floats            (CSR values)
    char* w = (char*)d_ws;
    float* buf0 = (float*)w;                 w += (size_t)maxN * EMB * sizeof(float);
    float* buf1 = (float*)w;                 w += (size_t)maxN * EMB * sizeof(float);
    int* ptr = (int*)w;                      w += (size_t)(maxN + 4) * sizeof(int);
    int* cnt = (int*)w;                      w += (size_t)(maxN + 4) * sizeof(int);
    int* ci = (int*)w;                       w += (size_t)maxE * sizeof(int);
    float* cv = (float*)w;

    long long out_off = 0;
    for (int gi = 0; gi < 3; ++gi) {
        const G& g = gs[gi];
        const int N = g.nA + g.nBn;
        float* acc = out + out_off;
        const long long rowTot = (long long)N * RD4;

        // --- CSR build ---
        hipMemsetAsync(cnt, 0, (size_t)N * sizeof(int), stream);
        hist_kernel<<<grid_for(g.E, 256), 256, 0, stream>>>(g.rows, g.E, cnt);
        scan_kernel<<<1, 1024, 0, stream>>>(N, cnt, ptr);
        scatter_kernel<<<grid_for(g.E, 256), 256, 0, stream>>>(
            g.rows, g.cols, g.vals, g.E, cnt, ci, cv);

        // --- init: cur = concat(fA,fB); acc = cur/3 ---
        init_concat_kernel<<<grid_for(rowTot, 256), 256, 0, stream>>>(
            g.fA, g.fB, g.nA, N, buf0, acc);

        // --- 2 layers of fused gather-SpMM + norm + accumulate ---
        float* cur = buf0;
        float* nxt = buf1;
        for (int layer = 0; layer < 2; ++layer) {
            int writeNext = (layer + 1 < 2) ? 1 : 0;
            spmm_norm_kernel<<<grid_for(rowTot, 256), 256, 0, stream>>>(
                ptr, ci, cv, cur, nxt, acc, N, writeNext);
            float* t = cur; cur = nxt; nxt = t;
        }
        out_off += (long long)N * EMB;
    }
}

// Round 3
// 1877.634 us; speedup vs baseline: 9.0484x; 1.3906x over previous
//
#include <hip/hip_runtime.h>

// LightGCN propagation, 3 bipartite graphs. Round 3: parallel two-level scan
// (the single-block scan was 1.02 ms of the 2.61 ms total).
// Per call, per graph: build CSR on device (histogram -> 2-level scan ->
// scatter), then 2x fused {gather-SpMM + row-L2-norm + acc += norm/3}.

constexpr int EMB = 64;
constexpr int RD4 = 16;              // float4 chunks per row
constexpr float THIRD = 1.0f / 3.0f;
constexpr float EPS_NRM = 1e-12f;
constexpr int SCAN_BLOCK = 256;
constexpr int SCAN_ITEMS = 8;        // per thread
constexpr int SCAN_TILE = SCAN_BLOCK * SCAN_ITEMS;  // 2048

__global__ void init_concat_kernel(const float* __restrict__ fA,
                                   const float* __restrict__ fB,
                                   int nA, int N,
                                   float* __restrict__ cur,
                                   float* __restrict__ acc) {
    long long total = (long long)N * RD4;
    long long stride = (long long)gridDim.x * blockDim.x;
    long long iA = (long long)nA * RD4;
    for (long long i = blockIdx.x * (long long)blockDim.x + threadIdx.x;
         i < total; i += stride) {
        float4 v = (i < iA) ? ((const float4*)fA)[i] : ((const float4*)fB)[i - iA];
        ((float4*)cur)[i] = v;
        ((float4*)acc)[i] = make_float4(v.x * THIRD, v.y * THIRD, v.z * THIRD, v.w * THIRD);
    }
}

__global__ void hist_kernel(const int* __restrict__ rows, long long E,
                            int* __restrict__ cnt) {
    long long stride = (long long)gridDim.x * blockDim.x;
    for (long long e = blockIdx.x * (long long)blockDim.x + threadIdx.x;
         e < E; e += stride) {
        atomicAdd(&cnt[rows[e]], 1);
    }
}

// --- two-level scan ---------------------------------------------------------
// A: per-tile partial sums.
__global__ void scan_partial_kernel(const int* __restrict__ cnt, int N,
                                    int* __restrict__ bsum) {
    __shared__ int red[SCAN_BLOCK];
    const int b = blockIdx.x;
    const int t = threadIdx.x;
    const int base = b * SCAN_TILE + t * SCAN_ITEMS;
    int s = 0;
    if (base + SCAN_ITEMS <= N) {
        int4 a = ((const int4*)cnt)[(base >> 2) + 0];
        int4 c = ((const int4*)cnt)[(base >> 2) + 1];
        s = a.x + a.y + a.z + a.w + c.x + c.y + c.z + c.w;
    } else {
        for (int k = 0; k < SCAN_ITEMS; ++k)
            if (base + k < N) s += cnt[base + k];
    }
    red[t] = s;
    __syncthreads();
    for (int off = SCAN_BLOCK / 2; off > 0; off >>= 1) {
        if (t < off) red[t] += red[t + off];
        __syncthreads();
    }
    if (t == 0) bsum[b] = red[0];
}

// B: single small block scans the <=1024 tile sums; bsum -> exclusive,
// bsum[NB] = grand total.
__global__ void scan_bsums_kernel(int* __restrict__ bsum, int NB) {
    __shared__ int s[1024];
    const int t = threadIdx.x;
    int v = (t < NB) ? bsum[t] : 0;
    s[t] = v;
    __syncthreads();
    for (int off = 1; off < 1024; off <<= 1) {
        int x = (t >= off) ? s[t - off] : 0;
        __syncthreads();
        s[t] += x;
        __syncthreads();
    }
    if (t < NB) bsum[t] = s[t] - v;      // exclusive prefix
    if (t == 1023) bsum[NB] = s[1023];   // total
}

// C: per-tile exclusive scan + tile offset; writes ptr[i] and rewrites cnt[i]
// to the exclusive prefix (scatter cursor). Also writes ptr[N].
__global__ void scan_apply_kernel(int* __restrict__ cnt, int N,
                                  const int* __restrict__ bsum, int NB,
                                  int* __restrict__ ptr) {
    __shared__ int tsum[SCAN_BLOCK];
    const int b = blockIdx.x;
    const int t = threadIdx.x;
    const int base = b * SCAN_TILE + t * SCAN_ITEMS;
    int v[SCAN_ITEMS];
    int s = 0;
    if (base + SCAN_ITEMS <= N) {
        int4 a = ((const int4*)cnt)[(base >> 2) + 0];
        int4 c = ((const int4*)cnt)[(base >> 2) + 1];
        v[0] = a.x; v[1] = a.y; v[2] = a.z; v[3] = a.w;
        v[4] = c.x; v[5] = c.y; v[6] = c.z; v[7] = c.w;
        s = v[0] + v[1] + v[2] + v[3] + v[4] + v[5] + v[6] + v[7];
    } else {
        for (int k = 0; k < SCAN_ITEMS; ++k) {
            v[k] = (base + k < N) ? cnt[base + k] : 0;
            s += v[k];
        }
    }
    tsum[t] = s;
    __syncthreads();
    // Hillis-Steele inclusive scan over thread sums
    for (int off = 1; off < SCAN_BLOCK; off <<= 1) {
        int x = (t >= off) ? tsum[t - off] : 0;
        __syncthreads();
        tsum[t] += x;
        __syncthreads();
    }
    int run = bsum[b] + tsum[t] - s;     // exclusive offset for this thread
    for (int k = 0; k < SCAN_ITEMS; ++k) {
        if (base + k < N) {
            ptr[base + k] = run;
            cnt[base + k] = run;         // scatter cursor
            run += v[k];
        }
    }
    if (b == 0 && t == 0) ptr[N] = bsum[NB];
}
// ----------------------------------------------------------------------------

__global__ void scatter_kernel(const int* __restrict__ rows,
                               const int* __restrict__ cols,
                               const float* __restrict__ vals,
                               long long E,
                               int* __restrict__ cursor,
                               int* __restrict__ ci,
                               float* __restrict__ cv) {
    long long stride = (long long)gridDim.x * blockDim.x;
    for (long long e = blockIdx.x * (long long)blockDim.x + threadIdx.x;
         e < E; e += stride) {
        int r = rows[e];
        int pos = atomicAdd(&cursor[r], 1);
        ci[pos] = cols[e];
        cv[pos] = vals[e];
    }
}

// 16 lanes own one output row (float4 per lane). Gather cur[col] over the
// row's CSR range, then fused: optional nxt write, row-L2-norm via
// quarter-wave shfl_xor, acc += s * (1/3)/max(||s||,eps).
__global__ void spmm_norm_kernel(const int* __restrict__ ptr,
                                 const int* __restrict__ ci,
                                 const float* __restrict__ cv,
                                 const float* __restrict__ cur,
                                 float* __restrict__ nxt,
                                 float* __restrict__ acc,
                                 int N, int writeNext) {
    int gid = (int)((blockIdx.x * (long long)blockDim.x + threadIdx.x) >> 4);
    int lane = threadIdx.x & 15;
    if (gid >= N) return;
    const int beg = ptr[gid];
    const int end = ptr[gid + 1];
    float4 s = make_float4(0.f, 0.f, 0.f, 0.f);
    for (int j = beg; j < end; ++j) {
        int c = ci[j];
        float v = cv[j];
        float4 g = ((const float4*)cur)[(long long)c * RD4 + lane];
        s.x += v * g.x;
        s.y += v * g.y;
        s.z += v * g.z;
        s.w += v * g.w;
    }
    const long long idx = (long long)gid * RD4 + lane;
    if (writeNext) ((float4*)nxt)[idx] = s;
    float ss = s.x * s.x + s.y * s.y + s.z * s.z + s.w * s.w;
    ss += __shfl_xor(ss, 1, 16);
    ss += __shfl_xor(ss, 2, 16);
    ss += __shfl_xor(ss, 4, 16);
    ss += __shfl_xor(ss, 8, 16);
    float scale = THIRD / fmaxf(sqrtf(ss), EPS_NRM);
    float4 a = ((float4*)acc)[idx];
    a.x += s.x * scale;
    a.y += s.y * scale;
    a.z += s.z * scale;
    a.w += s.w * scale;
    ((float4*)acc)[idx] = a;
}

static inline int grid_for(long long total, int block) {
    long long g = (total + block - 1) / block;
    if (g > (1LL << 20)) g = (1LL << 20);
    if (g < 1) g = 1;
    return (int)g;
}

extern "C" void kernel_launch(void* const* d_in, const int* in_sizes, int n_in,
                              void* d_out, int out_size, void* d_ws, size_t ws_size,
                              hipStream_t stream) {
    const float* fu = (const float*)d_in[0];
    const float* fb = (const float*)d_in[1];
    const float* fi = (const float*)d_in[2];
    const int nU = in_sizes[0] / EMB;
    const int nB = in_sizes[1] / EMB;
    const int nI = in_sizes[2] / EMB;
    float* out = (float*)d_out;

    struct G {
        const int* rows; const int* cols; const float* vals;
        long long E; const float* fA; const float* fB; int nA; int nBn;
    };
    G gs[3] = {
        { (const int*)d_in[3], (const int*)d_in[4], (const float*)d_in[5],
          (long long)in_sizes[3], fu, fb, nU, nB },
        { (const int*)d_in[6], (const int*)d_in[7], (const float*)d_in[8],
          (long long)in_sizes[6], fu, fi, nU, nI },
        { (const int*)d_in[9], (const int*)d_in[10], (const float*)d_in[11],
          (long long)in_sizes[9], fb, fi, nB, nI },
    };

    int maxN = 0;
    long long maxE = 0;
    for (int gi = 0; gi < 3; ++gi) {
        int N = gs[gi].nA + gs[gi].nBn;
        if (N > maxN) maxN = N;
        if (gs[gi].E > maxE) maxE = gs[gi].E;
    }
    const int maxNB = (maxN + SCAN_TILE - 1) / SCAN_TILE;

    // Workspace layout (16B-aligned chunks):
    char* w = (char*)d_ws;
    float* buf0 = (float*)w;                 w += (size_t)maxN * EMB * sizeof(float);
    float* buf1 = (float*)w;                 w += (size_t)maxN * EMB * sizeof(float);
    int* ptr = (int*)w;                      w += (size_t)((maxN + 8) & ~7) * sizeof(int);
    int* cnt = (int*)w;                      w += (size_t)((maxN + 8) & ~7) * sizeof(int);
    int* bsum = (int*)w;                     w += (size_t)((maxNB + 8) & ~7) * sizeof(int);
    int* ci = (int*)w;                       w += (size_t)maxE * sizeof(int);
    float* cv = (float*)w;

    long long out_off = 0;
    for (int gi = 0; gi < 3; ++gi) {
        const G& g = gs[gi];
        const int N = g.nA + g.nBn;
        const int NB = (N + SCAN_TILE - 1) / SCAN_TILE;
        float* acc = out + out_off;
        const long long rowTot = (long long)N * RD4;

        // --- CSR build ---
        hipMemsetAsync(cnt, 0, (size_t)N * sizeof(int), stream);
        hist_kernel<<<grid_for(g.E, 256), 256, 0, stream>>>(g.rows, g.E, cnt);
        scan_partial_kernel<<<NB, SCAN_BLOCK, 0, stream>>>(cnt, N, bsum);
        scan_bsums_kernel<<<1, 1024, 0, stream>>>(bsum, NB);
        scan_apply_kernel<<<NB, SCAN_BLOCK, 0, stream>>>(cnt, N, bsum, NB, ptr);
        scatter_kernel<<<grid_for(g.E, 256), 256, 0, stream>>>(
            g.rows, g.cols, g.vals, g.E, cnt, ci, cv);

        // --- init: cur = concat(fA,fB); acc = cur/3 ---
        init_concat_kernel<<<grid_for(rowTot, 256), 256, 0, stream>>>(
            g.fA, g.fB, g.nA, N, buf0, acc);

        // --- 2 layers of fused gather-SpMM + norm + accumulate ---
        float* cur = buf0;
        float* nxt = buf1;
        for (int layer = 0; layer < 2; ++layer) {
            int writeNext = (layer + 1 < 2) ? 1 : 0;
            spmm_norm_kernel<<<grid_for(rowTot, 256), 256, 0, stream>>>(
                ptr, ci, cv, cur, nxt, acc, N, writeNext);
            float* t = cur; cur = nxt; nxt = t;
        }
        out_off += (long long)N * EMB;
    }
}